// Round 10
// baseline (236.959 us; speedup 1.0000x reference)
//
#include <hip/hip_runtime.h>

// DFAProb: transposed-DFA fuzzy sum-product, semiring='prob'.
// Per row i (B = 2M rows, 8 states):
//   unnorm[ns] = s0[(ns-1)&7]*a*b + s0[(ns-2)&7]*a*(1-b) + s0[ns]*(1-a)
//   next = clip(unnorm/sum(unnorm), 1e-7, 1-1e-7)
//   outputs (concat flat): log(next) [B*8], next [B*8], next[:,7] [B]
// log_s0 input UNUSED by reference -> never read.
// History: R4 nt stores doubled WRITE_SIZE (L2 merge bypass) -> plain stores.
//   R7 exact-grid vs grid-stride: null. Both give kernel ~56us at ~3.2 TB/s
//   effective on ~180 MB HBM traffic (vs 6.3 TB/s copy ceiling).
// R8 theory: read-MLP-limited. 4 rows/thread spaced by grid stride: all 16
//   loads issue back-to-back (4x outstanding bytes/wave), every ld/st inst
//   still 1KB fully-coalesced. Fast path (no bounds checks) for 99.8% of
//   threads so the compiler batches the loads.
// R9: broker capacity timeout -> resubmit, no measurement.

#define DFA_EPS 1e-7f

typedef float f32x4 __attribute__((ext_vector_type(4)));

__device__ __forceinline__ void dfa_row_compute(
    const f32x4 lo, const f32x4 hi, const float av, const float bv,
    float* __restrict__ log_out, float* __restrict__ ns_out,
    float* __restrict__ acc_out, size_t i)
{
    const float ab  = av * bv;
    const float anb = av * (1.0f - bv);
    const float na  = 1.0f - av;

    const float s[8] = {lo.x, lo.y, lo.z, lo.w, hi.x, hi.y, hi.z, hi.w};

    float un[8];
    float denom = 0.0f;
#pragma unroll
    for (int n = 0; n < 8; ++n) {
        un[n] = fmaf(s[(n + 7) & 7], ab,
                fmaf(s[(n + 6) & 7], anb, s[n] * na));
        denom += un[n];
    }

    const float inv = 1.0f / denom;

    float nsv[8], lg[8];
#pragma unroll
    for (int n = 0; n < 8; ++n) {
        float v = un[n] * inv;
        v = fminf(fmaxf(v, DFA_EPS), 1.0f - DFA_EPS);
        nsv[n] = v;
        lg[n] = __logf(v);
    }

    f32x4* lg4 = reinterpret_cast<f32x4*>(log_out + i * 8);
    lg4[0] = (f32x4){lg[0], lg[1], lg[2], lg[3]};
    lg4[1] = (f32x4){lg[4], lg[5], lg[6], lg[7]};

    f32x4* ns4 = reinterpret_cast<f32x4*>(ns_out + i * 8);
    ns4[0] = (f32x4){nsv[0], nsv[1], nsv[2], nsv[3]};
    ns4[1] = (f32x4){nsv[4], nsv[5], nsv[6], nsv[7]};

    acc_out[i] = nsv[7];
}

__global__ __launch_bounds__(256) void dfa_prob_kernel(
    const float* __restrict__ s0,
    const float* __restrict__ a_in,
    const float* __restrict__ b_in,
    float* __restrict__ log_out,   // B*8
    float* __restrict__ ns_out,    // B*8
    float* __restrict__ acc_out,   // B
    int B)
{
    const int G = gridDim.x * blockDim.x;            // rows per k-slice
    const int i = blockIdx.x * blockDim.x + threadIdx.x;

    if ((size_t)i + 3 * (size_t)G < (size_t)B) {
        // Fast path: 4 rows, all loads issued before any use (deep MLP).
        const size_t r0 = (size_t)i;
        const size_t r1 = r0 + G;
        const size_t r2 = r1 + G;
        const size_t r3 = r2 + G;

        const float a0 = a_in[r0], a1 = a_in[r1], a2 = a_in[r2], a3 = a_in[r3];
        const float b0 = b_in[r0], b1 = b_in[r1], b2 = b_in[r2], b3 = b_in[r3];

        const f32x4* s4 = reinterpret_cast<const f32x4*>(s0);
        const f32x4 l0 = s4[r0 * 2], h0 = s4[r0 * 2 + 1];
        const f32x4 l1 = s4[r1 * 2], h1 = s4[r1 * 2 + 1];
        const f32x4 l2 = s4[r2 * 2], h2 = s4[r2 * 2 + 1];
        const f32x4 l3 = s4[r3 * 2], h3 = s4[r3 * 2 + 1];

        dfa_row_compute(l0, h0, a0, b0, log_out, ns_out, acc_out, r0);
        dfa_row_compute(l1, h1, a1, b1, log_out, ns_out, acc_out, r1);
        dfa_row_compute(l2, h2, a2, b2, log_out, ns_out, acc_out, r2);
        dfa_row_compute(l3, h3, a3, b3, log_out, ns_out, acc_out, r3);
    } else {
        // Tail: per-row bounds check.
#pragma unroll
        for (int k = 0; k < 4; ++k) {
            const size_t r = (size_t)i + (size_t)k * G;
            if (r < (size_t)B) {
                const f32x4* s4 = reinterpret_cast<const f32x4*>(s0 + r * 8);
                dfa_row_compute(s4[0], s4[1], a_in[r], b_in[r],
                                log_out, ns_out, acc_out, r);
            }
        }
    }
}

extern "C" void kernel_launch(void* const* d_in, const int* in_sizes, int n_in,
                              void* d_out, int out_size, void* d_ws, size_t ws_size,
                              hipStream_t stream) {
    // Inputs (setup_inputs order): log_s0 [B*8] (UNUSED), s0 [B*8], a [B], b [B]
    const float* s0 = (const float*)d_in[1];
    const float* a  = (const float*)d_in[2];
    const float* b  = (const float*)d_in[3];
    const int B = in_sizes[2];

    float* out = (float*)d_out;
    float* log_out = out;                         // [B*8]
    float* ns_out  = out + (size_t)B * 8;         // [B*8]
    float* acc_out = out + (size_t)B * 16;        // [B]

    const int block = 256;
    const int rows_per_thread = 4;
    const int grid = (B + block * rows_per_thread - 1) / (block * rows_per_thread);
    dfa_prob_kernel<<<grid, block, 0, stream>>>(s0, a, b, log_out, ns_out, acc_out, B);
}